// Round 1
// 77.544 us; speedup vs baseline: 1.0271x; 1.0271x over previous
//
#include <hip/hip_runtime.h>
#include <math.h>

#define N 512
#define TILE 32
#define TSTRIDE 34  // ts row stride in dwords: even -> aligned float2 writes, 2-way-conflict reads (free)
#define INV2PI 0.15915494309189535f

// ---- packed (2-element-per-lane) helpers on clang ext_vector floats ----
// ext_vector_type(2) float arithmetic lowers to VOP3P v_pk_{fma,mul,add}_f32 on
// gfx90a+ (CDNA2+), guaranteeing the 2x packed-f32 issue rate instead of relying
// on SLP to re-vectorize struct-of-scalar make_float2 code.
typedef float vf2 __attribute__((ext_vector_type(2)));

__device__ __forceinline__ vf2 pset(float a, float b) { vf2 r; r.x = a; r.y = b; return r; }
__device__ __forceinline__ vf2 psplat(float a) { return pset(a, a); }

__device__ __forceinline__ vf2 p_fma(vf2 a, vf2 b, vf2 c) {
#if __has_builtin(__builtin_elementwise_fma)
    return __builtin_elementwise_fma(a, b, c);
#else
    return pset(fmaf(a.x, b.x, c.x), fmaf(a.y, b.y, c.y));
#endif
}
// a*b - c*d (mul + fma, packed)
__device__ __forceinline__ vf2 p_fmsub(vf2 a, vf2 b, vf2 c, vf2 d) {
    return p_fma(a, b, -(c * d));
}
__device__ __forceinline__ vf2 p_rsq(vf2 a) {
    return pset(__builtin_amdgcn_rsqf(a.x), __builtin_amdgcn_rsqf(a.y));
}

struct F3P { vf2 x, y, z; };

__device__ __forceinline__ F3P pp_sub(F3P a, F3P b) {
    F3P r; r.x = a.x - b.x; r.y = a.y - b.y; r.z = a.z - b.z; return r;
}
__device__ __forceinline__ F3P pp_cross(F3P a, F3P b) {
    F3P c;
    c.x = p_fmsub(a.y, b.z, a.z, b.y);
    c.y = p_fmsub(a.z, b.x, a.x, b.z);
    c.z = p_fmsub(a.x, b.y, a.y, b.x);
    return c;
}
__device__ __forceinline__ vf2 pp_dot(F3P a, F3P b) {
    return p_fma(a.x, b.x, p_fma(a.y, b.y, a.z * b.z));
}

// Fused clamp + Abramowitz-Stegun 4.4.45 asin + sign restore. |err| <= 5e-5.
// Polynomial chain packed; sqrt/copysign stay scalar (no v_pk trans / pk min).
__device__ __forceinline__ vf2 p_asin_clamped(vf2 t) {
    vf2 ax = pset(fminf(fabsf(t.x), 1.f), fminf(fabsf(t.y), 1.f));
    vf2 p = p_fma(ax, psplat(-0.0187293f), psplat(0.0742610f));
    p = p_fma(ax, p, psplat(-0.2121144f));
    p = p_fma(ax, p, psplat(1.5707288f));
    vf2 om = psplat(1.0f) - ax;
    float sx = __builtin_amdgcn_sqrtf(om.x);
    float sy = __builtin_amdgcn_sqrtf(om.y);
    float rx = fmaf(-sx, p.x, 1.5707963267948966f);
    float ry = fmaf(-sy, p.y, 1.5707963267948966f);
    return pset(copysignf(rx, t.x), copysignf(ry, t.y));
}

// Two independent writhe evaluations, one per packed half.
// Reformulated: u=p1-p0, v=p3-p2, d0=p2-p0;
//   c0=d0xv, c3=d0xu, w=uxv, c1=w-c3, c2=w-c0, sign dot: w.d0 = -(sign dot).
// 3 crosses + 2 vector adds replace 4 crosses + 4 subs; d1/d2/d3 never built.
__device__ __forceinline__ vf2 wr_core2(F3P p0, F3P p1, F3P p2, F3P p3) {
    F3P u = pp_sub(p1, p0);
    F3P v = pp_sub(p3, p2);
    F3P d0 = pp_sub(p2, p0);

    F3P c0 = pp_cross(d0, v);
    F3P c3 = pp_cross(d0, u);
    F3P w  = pp_cross(u, v);
    F3P c1; c1.x = w.x - c3.x; c1.y = w.y - c3.y; c1.z = w.z - c3.z;
    F3P c2; c2.x = w.x - c0.x; c2.y = w.y - c0.y; c2.z = w.z - c0.z;

    vf2 svn = pp_dot(w, d0);  // = -(sign dot); sign(sv) = sign(-svn)

    vf2 q0 = pp_dot(c0, c0);
    vf2 q1 = pp_dot(c1, c1);
    vf2 q2 = pp_dot(c2, c2);
    vf2 q3 = pp_dot(c3, c3);

    vf2 t01 = pp_dot(c0, c1) * p_rsq(q0 * q1);
    vf2 t12 = pp_dot(c1, c2) * p_rsq(q1 * q2);
    vf2 t23 = pp_dot(c2, c3) * p_rsq(q2 * q3);
    vf2 t30 = pp_dot(c3, c0) * p_rsq(q3 * q0);

    vf2 a01 = p_asin_clamped(t01), a12 = p_asin_clamped(t12);
    vf2 a23 = p_asin_clamped(t23), a30 = p_asin_clamped(t30);
    vf2 omega = (a01 + a12) + (a23 + a30);

    // wr = omega*sign(-svn)/(2pi) = (omega ^ signbit(svn)) * (-1/(2pi)).
    float ox = __int_as_float(__float_as_int(omega.x) ^
                              (__float_as_int(svn.x) & 0x80000000));
    float oy = __int_as_float(__float_as_int(omega.y) ^
                              (__float_as_int(svn.y) & 0x80000000));
    return pset(ox * -INV2PI, oy * -INV2PI);
}

__device__ __forceinline__ F3P pack_pt4(float4 a, float4 b) {
    F3P r;
    r.x = pset(a.x, b.x);
    r.y = pset(a.y, b.y);
    r.z = pset(a.z, b.z);
    return r;
}
__device__ __forceinline__ F3P pack_pt(const float4* __restrict__ xs4, int i0, int i1) {
    return pack_pt4(xs4[i0], xs4[i1]);
}
__device__ __forceinline__ F3P splat_pt(const float4* __restrict__ xs4, int i) {
    float4 a = xs4[i];
    F3P r;
    r.x = psplat(a.x);
    r.y = psplat(a.y);
    r.z = psplat(a.z);
    return r;
}

// Branchless per-element index rule: out(lo,hi): lo>=1 & hi>=lo+2 -> segment
// (lo-1,hi-1); lo==0 & 2<=hi<=510 -> segment (0,hi). Clamped for speculative loads.
__device__ __forceinline__ void elem_idx(int gi, int gj, int& a, int& b, bool& valid) {
    const int lo = min(gi, gj), hi = max(gi, gj);
    const bool z = (lo == 0);
    a = z ? 0 : (lo - 1);
    b = z ? min(hi, 510) : (hi - 1);
    valid = z ? ((hi >= 2) && (hi <= 510)) : (hi >= lo + 2);
}

// One block per (upper-triangle tile pair, batch).
// Fast path (1 <= ti < tj): halves = ADJACENT columns (gj, gj+1) -> 3 unique
// column-point loads, one aligned float2 store per row-pair, one dwordx4
// store per thread in the transpose phase. Global stores of the direct tile
// are deferred past __syncthreads so the pre-barrier s_waitcnt vmcnt(0)
// only drains LDS traffic, not HBM store acks.
__global__ __launch_bounds__(256) void writhe_tile(const float* __restrict__ x,
                                                   float* __restrict__ out) {
    __shared__ __align__(16) float4 xs4[N];
    __shared__ __align__(16) float tsf[TILE * TSTRIDE];

    const int batch = blockIdx.y;

    // Coalesced float4 global read, stride-3 -> stride-4 repack into LDS.
    {
        const float4* src = (const float4*)(x + (size_t)batch * (N * 3));
        float* xsf = (float*)xs4;
        for (int i = threadIdx.x; i < (N * 3) / 4; i += blockDim.x) {
            float4 g = src[i];
            const int base = 4 * i;
            float vv[4] = {g.x, g.y, g.z, g.w};
#pragma unroll
            for (int j = 0; j < 4; ++j) {
                const int e = base + j;
                xsf[(e / 3) * 4 + (e % 3)] = vv[j];
            }
        }
    }

    // blockIdx.x -> (ti, tj), ti <= tj, among 16x16 tiles (136 pairs).
    int p = blockIdx.x;
    int ti = 0;
    while (p >= (N / TILE) - ti) { p -= (N / TILE) - ti; ++ti; }
    const int tj = ti + p;
    const bool diag = (ti == tj);

    __syncthreads();

    float* ob = out + (size_t)batch * (N * N);

    if (ti >= 1 && !diag) {
        // ---- fast path: index rule is unconditionally (gi-1, gj-1) ----
        const int cp = threadIdx.x & 15;  // column pair
        const int r = threadIdx.x >> 4;   // row in [0,16)
        const int gj0 = tj * TILE + 2 * cp;

        // 3 unique column points; halves share xs4[gj0].
        const float4 qa = xs4[gj0 - 1];
        const float4 qb = xs4[gj0];
        const float4 qc = xs4[gj0 + 1];
        const F3P P2 = pack_pt4(qa, qb);
        const F3P P3 = pack_pt4(qb, qc);

        float2 keep[2];
#pragma unroll
        for (int k = 0; k < 2; ++k) {
            const int rr = r + 16 * k;
            const int gi = ti * TILE + rr;
            const F3P P0 = splat_pt(xs4, gi - 1);
            const F3P P1 = splat_pt(xs4, gi);
            vf2 wr = wr_core2(P0, P1, P2, P3);
            // adjacency guard (only adjacent tiles can violate hi >= lo+2)
            const float vx = (gj0 >= gi + 2) ? wr.x : 0.f;
            const float vy = (gj0 + 1 >= gi + 2) ? wr.y : 0.f;
            keep[k] = make_float2(vx, vy);
            *(float2*)(tsf + rr * TSTRIDE + 2 * cp) = keep[k];  // aligned 8B, LDS
        }

        __syncthreads();

        // Direct-tile global stores, deferred past the barrier.
#pragma unroll
        for (int k = 0; k < 2; ++k) {
            const int gi = ti * TILE + r + 16 * k;
            *(float2*)(ob + (size_t)gi * N + gj0) = keep[k];  // aligned 8B
        }

        // Transpose write: thread (r2, g) stores 4 consecutive columns of one row.
        {
            const int r2 = threadIdx.x & 31;
            const int g = threadIdx.x >> 5;  // 0..7
            float4 o;
            o.x = tsf[(4 * g + 0) * TSTRIDE + r2];
            o.y = tsf[(4 * g + 1) * TSTRIDE + r2];
            o.z = tsf[(4 * g + 2) * TSTRIDE + r2];
            o.w = tsf[(4 * g + 3) * TSTRIDE + r2];
            *(float4*)(ob + (size_t)(tj * TILE + r2) * N + ti * TILE + 4 * g) = o;
        }
    } else {
        // ---- generic path (diag + ti==0 tiles) ----
        const int c = threadIdx.x & 31;
        const int r0 = threadIdx.x >> 5;
        const int gj = tj * TILE + c;

#pragma unroll
        for (int k = 0; k < 2; ++k) {
            const int rA = r0 + 8 * k;
            const int rB = rA + 16;
            const int giA = ti * TILE + rA;
            const int giB = ti * TILE + rB;

            int aA, bA, aB, bB;
            bool vA, vB;
            elem_idx(giA, gj, aA, bA, vA);
            elem_idx(giB, gj, aB, bB, vB);

            F3P P0 = pack_pt(xs4, aA, aB);
            F3P P1 = pack_pt(xs4, aA + 1, aB + 1);
            F3P P2 = pack_pt(xs4, bA, bB);
            F3P P3 = pack_pt(xs4, bA + 1, bB + 1);

            vf2 wr = wr_core2(P0, P1, P2, P3);
            const float vxA = vA ? wr.x : 0.f;
            const float vxB = vB ? wr.y : 0.f;

            ob[(size_t)giA * N + gj] = vxA;
            ob[(size_t)giB * N + gj] = vxB;
            if (!diag) {
                tsf[rA * TSTRIDE + c] = vxA;
                tsf[rB * TSTRIDE + c] = vxB;
            }
        }

        if (!diag) {
            __syncthreads();
#pragma unroll
            for (int k = 0; k < 4; ++k) {
                const int r2 = r0 + 8 * k;
                ob[(size_t)(tj * TILE + r2) * N + (ti * TILE + c)] = tsf[c * TSTRIDE + r2];
            }
        }
    }
}

extern "C" void kernel_launch(void* const* d_in, const int* in_sizes, int n_in,
                              void* d_out, int out_size, void* d_ws, size_t ws_size,
                              hipStream_t stream) {
    const float* x = (const float*)d_in[0];
    float* out = (float*)d_out;
    const int B = in_sizes[0] / (N * 3);

    const int ntiles = N / TILE;                   // 16
    const int npairs = ntiles * (ntiles + 1) / 2;  // 136

    dim3 block(256);
    dim3 grid(npairs, B);
    writhe_tile<<<grid, block, 0, stream>>>(x, out);
}

// Round 2
// 76.919 us; speedup vs baseline: 1.0355x; 1.0081x over previous
//
#include <hip/hip_runtime.h>
#include <math.h>

#define N 512
#define TILE 32
#define TSTRIDE 34  // ts row stride in dwords: even -> aligned float2 writes, 2-way-conflict reads (free)
#define INV2PI 0.15915494309189535f

// ---- packed (2-element-per-lane) helpers on clang ext_vector floats ----
typedef float vf2 __attribute__((ext_vector_type(2)));

__device__ __forceinline__ vf2 pset(float a, float b) { vf2 r; r.x = a; r.y = b; return r; }
__device__ __forceinline__ vf2 psplat(float a) { return pset(a, a); }

__device__ __forceinline__ vf2 p_fma(vf2 a, vf2 b, vf2 c) {
#if __has_builtin(__builtin_elementwise_fma)
    return __builtin_elementwise_fma(a, b, c);
#else
    return pset(fmaf(a.x, b.x, c.x), fmaf(a.y, b.y, c.y));
#endif
}
// a*b - c*d (mul + fma, packed)
__device__ __forceinline__ vf2 p_fmsub(vf2 a, vf2 b, vf2 c, vf2 d) {
    return p_fma(a, b, -(c * d));
}
__device__ __forceinline__ vf2 p_rsq(vf2 a) {
    return pset(__builtin_amdgcn_rsqf(a.x), __builtin_amdgcn_rsqf(a.y));
}

struct F3P { vf2 x, y, z; };

__device__ __forceinline__ F3P pp_sub(F3P a, F3P b) {
    F3P r; r.x = a.x - b.x; r.y = a.y - b.y; r.z = a.z - b.z; return r;
}
__device__ __forceinline__ F3P pp_cross(F3P a, F3P b) {
    F3P c;
    c.x = p_fmsub(a.y, b.z, a.z, b.y);
    c.y = p_fmsub(a.z, b.x, a.x, b.z);
    c.z = p_fmsub(a.x, b.y, a.y, b.x);
    return c;
}
__device__ __forceinline__ vf2 pp_dot(F3P a, F3P b) {
    return p_fma(a.x, b.x, p_fma(a.y, b.y, a.z * b.z));
}

// Fused clamp + Abramowitz-Stegun 4.4.45 asin + sign restore. |err| <= 5e-5.
__device__ __forceinline__ vf2 p_asin_clamped(vf2 t) {
    vf2 ax = pset(fminf(fabsf(t.x), 1.f), fminf(fabsf(t.y), 1.f));
    vf2 p = p_fma(ax, psplat(-0.0187293f), psplat(0.0742610f));
    p = p_fma(ax, p, psplat(-0.2121144f));
    p = p_fma(ax, p, psplat(1.5707288f));
    vf2 om = psplat(1.0f) - ax;
    float sx = __builtin_amdgcn_sqrtf(om.x);
    float sy = __builtin_amdgcn_sqrtf(om.y);
    float rx = fmaf(-sx, p.x, 1.5707963267948966f);
    float ry = fmaf(-sy, p.y, 1.5707963267948966f);
    return pset(copysignf(rx, t.x), copysignf(ry, t.y));
}

// Two independent writhe evaluations, one per packed half.
// u=p1-p0, v=p3-p2, d0=p2-p0; c0=d0xv, c3=d0xu, w=uxv, c1=w-c3, c2=w-c0,
// sign dot: w.d0 = -(sign dot). Identities verified symbolically.
__device__ __forceinline__ vf2 wr_core2(F3P p0, F3P p1, F3P p2, F3P p3) {
    F3P u = pp_sub(p1, p0);
    F3P v = pp_sub(p3, p2);
    F3P d0 = pp_sub(p2, p0);

    F3P c0 = pp_cross(d0, v);
    F3P c3 = pp_cross(d0, u);
    F3P w  = pp_cross(u, v);
    F3P c1; c1.x = w.x - c3.x; c1.y = w.y - c3.y; c1.z = w.z - c3.z;
    F3P c2; c2.x = w.x - c0.x; c2.y = w.y - c0.y; c2.z = w.z - c0.z;

    vf2 svn = pp_dot(w, d0);  // = -(sign dot); sign(sv) = sign(-svn)

    vf2 q0 = pp_dot(c0, c0);
    vf2 q1 = pp_dot(c1, c1);
    vf2 q2 = pp_dot(c2, c2);
    vf2 q3 = pp_dot(c3, c3);

    vf2 t01 = pp_dot(c0, c1) * p_rsq(q0 * q1);
    vf2 t12 = pp_dot(c1, c2) * p_rsq(q1 * q2);
    vf2 t23 = pp_dot(c2, c3) * p_rsq(q2 * q3);
    vf2 t30 = pp_dot(c3, c0) * p_rsq(q3 * q0);

    vf2 a01 = p_asin_clamped(t01), a12 = p_asin_clamped(t12);
    vf2 a23 = p_asin_clamped(t23), a30 = p_asin_clamped(t30);
    vf2 omega = (a01 + a12) + (a23 + a30);

    // wr = omega*sign(-svn)/(2pi) = (omega ^ signbit(svn)) * (-1/(2pi)).
    float ox = __int_as_float(__float_as_int(omega.x) ^
                              (__float_as_int(svn.x) & 0x80000000));
    float oy = __int_as_float(__float_as_int(omega.y) ^
                              (__float_as_int(svn.y) & 0x80000000));
    return pset(ox * -INV2PI, oy * -INV2PI);
}

__device__ __forceinline__ F3P pack_pt4(float4 a, float4 b) {
    F3P r;
    r.x = pset(a.x, b.x);
    r.y = pset(a.y, b.y);
    r.z = pset(a.z, b.z);
    return r;
}
__device__ __forceinline__ F3P pack_pt(const float4* __restrict__ xs4, int i0, int i1) {
    return pack_pt4(xs4[i0], xs4[i1]);
}
__device__ __forceinline__ F3P splat_pt(const float4* __restrict__ xs4, int i) {
    float4 a = xs4[i];
    F3P r;
    r.x = psplat(a.x);
    r.y = psplat(a.y);
    r.z = psplat(a.z);
    return r;
}

// Branchless per-element index rule: out(lo,hi): lo>=1 & hi>=lo+2 -> segment
// (lo-1,hi-1); lo==0 & 2<=hi<=510 -> segment (0,hi). Clamped for speculative loads.
__device__ __forceinline__ void elem_idx(int gi, int gj, int& a, int& b, bool& valid) {
    const int lo = min(gi, gj), hi = max(gi, gj);
    const bool z = (lo == 0);
    a = z ? 0 : (lo - 1);
    b = z ? min(hi, 510) : (hi - 1);
    valid = z ? ((hi >= 2) && (hi <= 510)) : (hi >= lo + 2);
}

// One block per (upper-triangle tile pair, batch).
// Occupancy-focused build: __launch_bounds__(256,4) caps VGPR at 128
// (4 waves/SIMD, 4 blocks/CU); the two wr_core2 evaluations run under
// #pragma unroll 1 so only one call body's registers are ever live; results
// go to LDS only, and the direct-tile global stores re-read them from LDS
// after the barrier so no value is register-carried across it.
__global__ __launch_bounds__(256, 4) void writhe_tile(const float* __restrict__ x,
                                                      float* __restrict__ out) {
    __shared__ __align__(16) float4 xs4[N];
    __shared__ __align__(16) float tsf[TILE * TSTRIDE];

    const int batch = blockIdx.y;

    // Coalesced float4 global read, stride-3 -> stride-4 repack into LDS.
    {
        const float4* src = (const float4*)(x + (size_t)batch * (N * 3));
        float* xsf = (float*)xs4;
        for (int i = threadIdx.x; i < (N * 3) / 4; i += blockDim.x) {
            float4 g = src[i];
            const int base = 4 * i;
            float vv[4] = {g.x, g.y, g.z, g.w};
#pragma unroll
            for (int j = 0; j < 4; ++j) {
                const int e = base + j;
                xsf[(e / 3) * 4 + (e % 3)] = vv[j];
            }
        }
    }

    // blockIdx.x -> (ti, tj), ti <= tj, among 16x16 tiles (136 pairs).
    int p = blockIdx.x;
    int ti = 0;
    while (p >= (N / TILE) - ti) { p -= (N / TILE) - ti; ++ti; }
    const int tj = ti + p;
    const bool diag = (ti == tj);

    __syncthreads();

    float* ob = out + (size_t)batch * (N * N);

    if (ti >= 1 && !diag) {
        // ---- fast path: index rule is unconditionally (gi-1, gj-1) ----
        const int cp = threadIdx.x & 15;  // column pair
        const int r = threadIdx.x >> 4;   // row in [0,16)
        const int gj0 = tj * TILE + 2 * cp;

        // 3 unique column points; halves share xs4[gj0].
        const float4 qa = xs4[gj0 - 1];
        const float4 qb = xs4[gj0];
        const float4 qc = xs4[gj0 + 1];
        const F3P P2 = pack_pt4(qa, qb);
        const F3P P3 = pack_pt4(qb, qc);

#pragma unroll 1
        for (int k = 0; k < 2; ++k) {
            const int rr = r + 16 * k;
            const int gi = ti * TILE + rr;
            const F3P P0 = splat_pt(xs4, gi - 1);
            const F3P P1 = splat_pt(xs4, gi);
            vf2 wr = wr_core2(P0, P1, P2, P3);
            // adjacency guard (only adjacent tiles can violate hi >= lo+2)
            const float vx = (gj0 >= gi + 2) ? wr.x : 0.f;
            const float vy = (gj0 + 1 >= gi + 2) ? wr.y : 0.f;
            *(float2*)(tsf + rr * TSTRIDE + 2 * cp) = make_float2(vx, vy);  // LDS only
        }

        __syncthreads();

        // Direct-tile global stores: re-read own slots from LDS (no registers
        // carried across the barrier).
#pragma unroll
        for (int k = 0; k < 2; ++k) {
            const int rr = r + 16 * k;
            const int gi = ti * TILE + rr;
            const float2 v = *(const float2*)(tsf + rr * TSTRIDE + 2 * cp);
            *(float2*)(ob + (size_t)gi * N + gj0) = v;  // aligned 8B
        }

        // Transpose write: thread (r2, g) stores 4 consecutive columns of one row.
        {
            const int r2 = threadIdx.x & 31;
            const int g = threadIdx.x >> 5;  // 0..7
            float4 o;
            o.x = tsf[(4 * g + 0) * TSTRIDE + r2];
            o.y = tsf[(4 * g + 1) * TSTRIDE + r2];
            o.z = tsf[(4 * g + 2) * TSTRIDE + r2];
            o.w = tsf[(4 * g + 3) * TSTRIDE + r2];
            *(float4*)(ob + (size_t)(tj * TILE + r2) * N + ti * TILE + 4 * g) = o;
        }
    } else {
        // ---- generic path (diag + ti==0 tiles) ----
        const int c = threadIdx.x & 31;
        const int r0 = threadIdx.x >> 5;
        const int gj = tj * TILE + c;

#pragma unroll 1
        for (int k = 0; k < 2; ++k) {
            const int rA = r0 + 8 * k;
            const int rB = rA + 16;
            const int giA = ti * TILE + rA;
            const int giB = ti * TILE + rB;

            int aA, bA, aB, bB;
            bool vA, vB;
            elem_idx(giA, gj, aA, bA, vA);
            elem_idx(giB, gj, aB, bB, vB);

            F3P P0 = pack_pt(xs4, aA, aB);
            F3P P1 = pack_pt(xs4, aA + 1, aB + 1);
            F3P P2 = pack_pt(xs4, bA, bB);
            F3P P3 = pack_pt(xs4, bA + 1, bB + 1);

            vf2 wr = wr_core2(P0, P1, P2, P3);
            const float vxA = vA ? wr.x : 0.f;
            const float vxB = vB ? wr.y : 0.f;

            ob[(size_t)giA * N + gj] = vxA;
            ob[(size_t)giB * N + gj] = vxB;
            if (!diag) {
                tsf[rA * TSTRIDE + c] = vxA;
                tsf[rB * TSTRIDE + c] = vxB;
            }
        }

        if (!diag) {
            __syncthreads();
#pragma unroll
            for (int k = 0; k < 4; ++k) {
                const int r2 = r0 + 8 * k;
                ob[(size_t)(tj * TILE + r2) * N + (ti * TILE + c)] = tsf[c * TSTRIDE + r2];
            }
        }
    }
}

extern "C" void kernel_launch(void* const* d_in, const int* in_sizes, int n_in,
                              void* d_out, int out_size, void* d_ws, size_t ws_size,
                              hipStream_t stream) {
    const float* x = (const float*)d_in[0];
    float* out = (float*)d_out;
    const int B = in_sizes[0] / (N * 3);

    const int ntiles = N / TILE;                   // 16
    const int npairs = ntiles * (ntiles + 1) / 2;  // 136

    dim3 block(256);
    dim3 grid(npairs, B);
    writhe_tile<<<grid, block, 0, stream>>>(x, out);
}